// Round 10
// baseline (423.131 us; speedup 1.0000x reference)
//
#include <hip/hip_runtime.h>
#include <hip/hip_bf16.h>
#include <math.h>
#include <stdint.h>

typedef __attribute__((ext_vector_type(8))) short bf16x8;
typedef __attribute__((ext_vector_type(4))) float floatx4;

static __device__ __forceinline__ unsigned short f32_to_bf16_rne(float f) {
    union { float f; uint32_t u; } v; v.f = f;
    uint32_t u = v.u;
    return (unsigned short)((u + 0x7fffu + ((u >> 16) & 1u)) >> 16);
}
static __device__ __forceinline__ float bf16_to_f32(unsigned short h) {
    union { uint32_t u; float f; } v; v.u = ((uint32_t)h) << 16;
    return v.f;
}

// 8 fp32 -> bf16x8 via HW v_cvt_pk_bf16_f32 (RNE)
static __device__ __forceinline__ bf16x8 cvt8(float4 a, float4 b) {
    union { __hip_bfloat162 h[4]; bf16x8 v; } u;
    u.h[0] = __float22bfloat162_rn({a.x, a.y});
    u.h[1] = __float22bfloat162_rn({a.z, a.w});
    u.h[2] = __float22bfloat162_rn({b.x, b.y});
    u.h[3] = __float22bfloat162_rn({b.z, b.w});
    return u.v;
}

// ---------------------------------------------------------------------------
// Prep: W1a (50x318) -> hi/lo bf16, fragment-ordered:
// byte = ks*8192 + p*4096 + kq*1024 + n*16  (n in [0,64), zero-padded)
// ---------------------------------------------------------------------------
__global__ void prep_w(const float* __restrict__ W1a, unsigned short* __restrict__ Bpre) {
    int idx = blockIdx.x * 256 + threadIdx.x;
    if (idx >= 40960) return;
    int e  = idx & 7;
    int n  = (idx >> 3) & 63;
    int kq = (idx >> 9) & 3;
    int p  = (idx >> 11) & 1;
    int ks = idx >> 12;
    int k  = ks * 32 + kq * 8 + e;
    float w = (n < 50 && k < 318) ? W1a[n * 318 + k] : 0.0f;
    unsigned short hi = f32_to_bf16_rne(w);
    Bpre[idx] = (p == 0) ? hi : f32_to_bf16_rne(w - bf16_to_f32(hi));
}

// ---------------------------------------------------------------------------
// Kernel A: 8192 blocks (one 64-token slab each), 256 threads, 4 blocks/CU.
// NO A-tile LDS: each wave loads its MFMA A-fragments (32B contiguous per
// lane, 16 rows x 128B per wave inst) DIRECTLY from global, converts to bf16
// in registers (v_cvt_pk_bf16_f32), MFMAs. B hi/lo transient per K-step from
// L2-hot Bpre. Zero barriers in GEMM; one __syncthreads for the h1 exchange.
// Waves free-run -> HBM demand stays continuous across blocks.
// ---------------------------------------------------------------------------
#define H1S 55
#define SLAB (64 * 318)

__global__ __launch_bounds__(256, 4)
void fused_mlp(const float* __restrict__ x,
               const unsigned short* __restrict__ Bpre,
               const float* __restrict__ b1a,
               const float* __restrict__ W1b, const float* __restrict__ b1b,
               const float* __restrict__ W1c, const float* __restrict__ b1c,
               const float* __restrict__ pW1, const float* __restrict__ pb1,
               const float* __restrict__ pW2, const float* __restrict__ pb2,
               float* __restrict__ partials)
{
    __shared__ __align__(16) float h1[64 * H1S];   // 14080 B

    const int tid  = threadIdx.x;
    const int wv   = tid >> 6;
    const int lane = tid & 63;
    const int fr   = lane & 15;
    const int kq   = lane >> 4;

    // per-lane A base: row fr (m-frag 0), k-offset kq*8
    const float* abase = x + (size_t)blockIdx.x * SLAB + fr * 318 + kq * 8;
    // per-lane B base: wave's n-slice [16w,16w+16)
    const char* bbase = (const char*)Bpre + (kq << 10) + ((wv * 16 + fr) << 4);

    floatx4 acc[4];
    #pragma unroll
    for (int mi = 0; mi < 4; ++mi) acc[mi] = (floatx4){0.f, 0.f, 0.f, 0.f};

    #pragma unroll
    for (int ks = 0; ks < 10; ++ks) {
        // B hi/lo fragments for this K-step (L2-hot)
        bf16x8 Bh = *(const bf16x8*)(bbase + ks * 8192);
        bf16x8 Bl = *(const bf16x8*)(bbase + ks * 8192 + 4096);

        #pragma unroll
        for (int mi = 0; mi < 4; ++mi) {
            const float* ap = abase + mi * (16 * 318) + ks * 32;
            float4 fa = *(const float4*)ap;
            float4 fb;
            if (ks == 9 && kq == 3) {           // k=312..319: pad 318,319
                float2 t = *(const float2*)(ap + 4);
                fb = make_float4(t.x, t.y, 0.f, 0.f);
            } else {
                fb = *(const float4*)(ap + 4);
            }
            bf16x8 a = cvt8(fa, fb);
            acc[mi] = __builtin_amdgcn_mfma_f32_16x16x32_bf16(a, Bh, acc[mi], 0, 0, 0);
            acc[mi] = __builtin_amdgcn_mfma_f32_16x16x32_bf16(a, Bl, acc[mi], 0, 0, 0);
        }
    }

    // ---- bias + ReLU -> h1 [64][55]
    {
        const int n = wv * 16 + fr;
        if (n < 50) {
            float bia = b1a[n];
            #pragma unroll
            for (int mi = 0; mi < 4; ++mi)
                #pragma unroll
                for (int r = 0; r < 4; ++r)
                    h1[(mi * 16 + kq * 4 + r) * H1S + n] =
                        fmaxf(acc[mi][r] + bia, 0.0f);
        }
    }
    __syncthreads();

    // ---- tail: every thread full layer2/3 + score for token = lane
    // (4 waves redundant; no further barriers)
    const float* h1r = h1 + lane * H1S;

    float h2[20];
    #pragma unroll
    for (int o = 0; o < 20; ++o) h2[o] = b1b[o];
    #pragma unroll
    for (int i = 0; i < 50; ++i) {
        float hv = h1r[i];
        #pragma unroll
        for (int o = 0; o < 20; ++o) h2[o] = fmaf(hv, W1b[o * 50 + i], h2[o]);
    }
    #pragma unroll
    for (int o = 0; o < 20; ++o) h2[o] = fmaxf(h2[o], 0.0f);

    float h3[20];
    #pragma unroll
    for (int o = 0; o < 20; ++o) {
        float a = b1c[o];
        const float* w = W1c + o * 20;
        #pragma unroll
        for (int i = 0; i < 20; ++i) a = fmaf(h2[i], w[i], a);
        h3[o] = fmaxf(a, 0.0f);
    }

    float s = pb2[0];
    #pragma unroll
    for (int j = 0; j < 10; ++j) {
        float a = pb1[j];
        const float* w = pW1 + j * 20;
        #pragma unroll
        for (int i = 0; i < 20; ++i) a = fmaf(h3[i], w[i], a);
        s = fmaf(fmaxf(a, 0.0f), pW2[j], s);
    }

    // softmax partial over this slab's 64 tokens
    float m = s;
    #pragma unroll
    for (int d = 32; d > 0; d >>= 1) m = fmaxf(m, __shfl_xor(m, d));
    float e = expf(s - m);
    float S = e;
    #pragma unroll
    for (int d = 32; d > 0; d >>= 1) S += __shfl_xor(S, d);

    float V[20];
    #pragma unroll
    for (int o = 0; o < 20; ++o) {
        float v = e * h3[o];
        #pragma unroll
        for (int d = 32; d > 0; d >>= 1) v += __shfl_xor(v, d);
        V[o] = v;
    }

    if (wv == 0) {
        float myv = m;
        if (lane == 1) myv = S;
        #pragma unroll
        for (int o = 0; o < 20; ++o) if (lane == o + 2) myv = V[o];
        if (lane < 22) partials[(size_t)blockIdx.x * 24 + lane] = myv;
    }
}

// ---------------------------------------------------------------------------
// Kernel B: combine half-group partials, pool over G=128, normalize, head.
// ---------------------------------------------------------------------------
__global__ __launch_bounds__(128, 4)
void pool_g_head(const float* __restrict__ partials,
                 const float* __restrict__ qW1, const float* __restrict__ qb1,
                 const float* __restrict__ qW2, const float* __restrict__ qb2,
                 const float* __restrict__ W3a, const float* __restrict__ b3a,
                 const float* __restrict__ W3b, const float* __restrict__ b3b,
                 float* __restrict__ out)
{
    __shared__ float red_m[2];
    __shared__ float red_s[2];
    __shared__ float part[2][20];

    const int tid = threadIdx.x;      // g
    const int b = blockIdx.x;
    const float* P = partials + ((size_t)(b * 128 + tid)) * 48;

    float m0 = P[0], S0 = P[1], m1 = P[24], S1 = P[25];
    float m = fmaxf(m0, m1);
    float w0 = expf(m0 - m), w1 = expf(m1 - m);
    float den = fmaf(S0, w0, S1 * w1);

    float v[20];
    #pragma unroll
    for (int o = 0; o < 20; ++o)
        v[o] = fmaf(P[2 + o], w0, P[26 + o] * w1) / den;

    float s = qb2[0];
    #pragma unroll
    for (int j = 0; j < 10; ++j) {
        float a = qb1[j];
        const float* w = qW1 + j * 20;
        #pragma unroll
        for (int i = 0; i < 20; ++i) a = fmaf(v[i], w[i], a);
        s = fmaf(fmaxf(a, 0.0f), qW2[j], s);
    }

    const int wig = tid >> 6, lane = tid & 63;
    float mm = s;
    #pragma unroll
    for (int d = 32; d > 0; d >>= 1) mm = fmaxf(mm, __shfl_xor(mm, d));
    if (lane == 0) red_m[wig] = mm;
    __syncthreads();
    mm = fmaxf(red_m[0], red_m[1]);

    float e = expf(s - mm);
    float su = e;
    #pragma unroll
    for (int d = 32; d > 0; d >>= 1) su += __shfl_xor(su, d);
    if (lane == 0) red_s[wig] = su;

    #pragma unroll
    for (int o = 0; o < 20; ++o) {
        float val = e * v[o];
        #pragma unroll
        for (int d = 32; d > 0; d >>= 1) val += __shfl_xor(val, d);
        if (lane == 0) part[wig][o] = val;
    }
    __syncthreads();

    if (tid == 0) {
        float dg = red_s[0] + red_s[1];
        float rb[20];
        float n2 = 0.0f;
        #pragma unroll
        for (int o = 0; o < 20; ++o) {
            rb[o] = (part[0][o] + part[1][o]) / dg;
            n2 = fmaf(rb[o], rb[o], n2);
        }
        float nrm = fmaxf(sqrtf(n2), 1e-12f);
        #pragma unroll
        for (int o = 0; o < 20; ++o) rb[o] /= nrm;

        float accv = b3b[0];
        #pragma unroll
        for (int j = 0; j < 10; ++j) {
            float a = b3a[j];
            const float* w = W3a + j * 20;
            #pragma unroll
            for (int i = 0; i < 20; ++i) a = fmaf(rb[i], w[i], a);
            accv = fmaf(fmaxf(a, 0.0f), W3b[j], accv);
        }
        out[b] = accv;
    }
}

extern "C" void kernel_launch(void* const* d_in, const int* in_sizes, int n_in,
                              void* d_out, int out_size, void* d_ws, size_t ws_size,
                              hipStream_t stream) {
    const float* x   = (const float*)d_in[0];
    const float* W1a = (const float*)d_in[1];
    const float* b1a = (const float*)d_in[2];
    const float* W1b = (const float*)d_in[3];
    const float* b1b = (const float*)d_in[4];
    const float* W1c = (const float*)d_in[5];
    const float* b1c = (const float*)d_in[6];
    const float* pW1 = (const float*)d_in[7];
    const float* pb1 = (const float*)d_in[8];
    const float* pW2 = (const float*)d_in[9];
    const float* pb2 = (const float*)d_in[10];
    const float* qW1 = (const float*)d_in[11];
    const float* qb1 = (const float*)d_in[12];
    const float* qW2 = (const float*)d_in[13];
    const float* qb2 = (const float*)d_in[14];
    const float* W3a = (const float*)d_in[15];
    const float* b3a = (const float*)d_in[16];
    const float* W3b = (const float*)d_in[17];
    const float* b3b = (const float*)d_in[18];

    float* partials      = (float*)d_ws;                             // 786,432 B
    unsigned short* Bpre = (unsigned short*)((char*)d_ws + 786432);  // 81,920 B

    prep_w<<<160, 256, 0, stream>>>(W1a, Bpre);
    fused_mlp<<<8192, 256, 0, stream>>>(
        x, Bpre, b1a, W1b, b1b, W1c, b1c, pW1, pb1, pW2, pb2, partials);
    pool_g_head<<<32, 128, 0, stream>>>(
        partials, qW1, qb1, qW2, qb2, W3a, b3a, W3b, b3b, (float*)d_out);
}

// Round 11
// 344.974 us; speedup vs baseline: 1.2266x; 1.2266x over previous
//
#include <hip/hip_runtime.h>
#include <math.h>
#include <stdint.h>

typedef __attribute__((ext_vector_type(8))) short bf16x8;
typedef __attribute__((ext_vector_type(4))) float floatx4;

static __device__ __forceinline__ unsigned short f32_to_bf16_rne(float f) {
    union { float f; uint32_t u; } v; v.f = f;
    uint32_t u = v.u;
    return (unsigned short)((u + 0x7fffu + ((u >> 16) & 1u)) >> 16);
}
static __device__ __forceinline__ float bf16_to_f32(unsigned short h) {
    union { uint32_t u; float f; } v; v.u = ((uint32_t)h) << 16;
    return v.f;
}
static __device__ __forceinline__ uint32_t pack2(float2 a) {
    return (uint32_t)f32_to_bf16_rne(a.x) | ((uint32_t)f32_to_bf16_rne(a.y) << 16);
}

// ---------------------------------------------------------------------------
// Prep: W1a (50x318) -> hi/lo bf16, fragment-ordered:
// byte = ks*8192 + p*4096 + kq*1024 + n*16  (n in [0,64), zero-padded)
// ---------------------------------------------------------------------------
__global__ void prep_w(const float* __restrict__ W1a, unsigned short* __restrict__ Bpre) {
    int idx = blockIdx.x * 256 + threadIdx.x;
    if (idx >= 40960) return;
    int e  = idx & 7;
    int n  = (idx >> 3) & 63;
    int kq = (idx >> 9) & 3;
    int p  = (idx >> 11) & 1;
    int ks = idx >> 12;
    int k  = ks * 32 + kq * 8 + e;
    float w = (n < 50 && k < 318) ? W1a[n * 318 + k] : 0.0f;
    unsigned short hi = f32_to_bf16_rne(w);
    Bpre[idx] = (p == 0) ? hi : f32_to_bf16_rne(w - bf16_to_f32(hi));
}

// ---------------------------------------------------------------------------
// Kernel A: 8192 blocks x 128 threads (2 INDEPENDENT waves). Each wave owns
// a 32-token slab and the FULL N=50: wave-private LDS plane (32x336B),
// wave-private staging bursts (20 float2 in flight), per-ks transient B
// (L2-hot), h1 exchange via own plane. ZERO barriers until a single
// end-of-kernel 2-wave partial merge. 7 blocks/CU = 14 free-running waves.
// ---------------------------------------------------------------------------
#define WPLANE 10752           // 32 rows x 336 B
#define H1S 51                 // h1 row stride (floats), gcd(51,32)=1
#define SLAB (64 * 318)

__global__ __launch_bounds__(128, 4)
void fused_mlp(const float* __restrict__ x,
               const unsigned short* __restrict__ Bpre,
               const float* __restrict__ b1a,
               const float* __restrict__ W1b, const float* __restrict__ b1b,
               const float* __restrict__ W1c, const float* __restrict__ b1c,
               const float* __restrict__ pW1, const float* __restrict__ pb1,
               const float* __restrict__ pW2, const float* __restrict__ pb2,
               float* __restrict__ partials)
{
    __shared__ __align__(16) char smem[2 * WPLANE + 192];

    const int tid  = threadIdx.x;
    const int wv   = tid >> 6;
    const int lane = tid & 63;
    const int fr   = lane & 15;
    const int kq   = lane >> 4;

    // wave's 32-token slab (contiguous 40 KB of x)
    const float* wslab = x + (size_t)blockIdx.x * SLAB + wv * (32 * 318);
    char* pl = smem + wv * WPLANE;

    floatx4 acc0[4], acc1[4];
    #pragma unroll
    for (int nf = 0; nf < 4; ++nf) {
        acc0[nf] = (floatx4){0.f, 0.f, 0.f, 0.f};
        acc1[nf] = (floatx4){0.f, 0.f, 0.f, 0.f};
    }

    #pragma unroll
    for (int half = 0; half < 2; ++half) {
        const int koff = half * 160;
        // ---- stage this K-half: rows 0..15 then 16..31 (20 float2 bursts)
        float2 ga[20], gb[20];
        #pragma unroll
        for (int j = 0; j < 20; ++j) {
            int f = j * 64 + lane; int r = f / 80, c = f - r * 80;
            bool pad = (half == 1) && (c == 79);          // k = 318,319
            ga[j] = pad ? make_float2(0.f, 0.f)
                        : *(const float2*)(wslab + r * 318 + koff + 2 * c);
        }
        #pragma unroll
        for (int j = 0; j < 20; ++j) {
            int f = j * 64 + lane; int r = f / 80, c = f - r * 80;
            bool pad = (half == 1) && (c == 79);
            gb[j] = pad ? make_float2(0.f, 0.f)
                        : *(const float2*)(wslab + (16 + r) * 318 + koff + 2 * c);
        }
        #pragma unroll
        for (int j = 0; j < 20; ++j) {
            int f = j * 64 + lane; int r = f / 80, c = f - r * 80;
            *(uint32_t*)(pl + r * 336 + c * 4) = pack2(ga[j]);
        }
        #pragma unroll
        for (int j = 0; j < 20; ++j) {
            int f = j * 64 + lane; int r = f / 80, c = f - r * 80;
            *(uint32_t*)(pl + (16 + r) * 336 + c * 4) = pack2(gb[j]);
        }
        // same-wave write->read ordering (no barrier needed)
        asm volatile("s_waitcnt lgkmcnt(0)" ::: "memory");

        // ---- 5 K-steps: A from own plane, B (hi/lo, all 4 n-frags) from L2
        #pragma unroll
        for (int ksl = 0; ksl < 5; ++ksl) {
            const int ks = half * 5 + ksl;
            const char* bb = (const char*)Bpre + ks * 8192 + (kq << 10) + (fr << 4);
            bf16x8 Bh[4], Bl[4];
            #pragma unroll
            for (int nf = 0; nf < 4; ++nf) {
                Bh[nf] = *(const bf16x8*)(bb + nf * 256);
                Bl[nf] = *(const bf16x8*)(bb + 4096 + nf * 256);
            }
            bf16x8 a0 = *(const bf16x8*)(pl + fr * 336 + kq * 16 + ksl * 64);
            bf16x8 a1 = *(const bf16x8*)(pl + (16 + fr) * 336 + kq * 16 + ksl * 64);
            #pragma unroll
            for (int nf = 0; nf < 4; ++nf) {
                acc0[nf] = __builtin_amdgcn_mfma_f32_16x16x32_bf16(a0, Bh[nf], acc0[nf], 0, 0, 0);
                acc0[nf] = __builtin_amdgcn_mfma_f32_16x16x32_bf16(a0, Bl[nf], acc0[nf], 0, 0, 0);
                acc1[nf] = __builtin_amdgcn_mfma_f32_16x16x32_bf16(a1, Bh[nf], acc1[nf], 0, 0, 0);
                acc1[nf] = __builtin_amdgcn_mfma_f32_16x16x32_bf16(a1, Bl[nf], acc1[nf], 0, 0, 0);
            }
        }
    }

    // ---- bias + ReLU -> h1 [32][51] f32 in own plane (plane data dead)
    {
        float* h1 = (float*)pl;
        #pragma unroll
        for (int nf = 0; nf < 4; ++nf) {
            int n = nf * 16 + fr;
            if (n < 50) {
                float bia = b1a[n];
                #pragma unroll
                for (int r = 0; r < 4; ++r) {
                    h1[(kq * 4 + r) * H1S + n]      = fmaxf(acc0[nf][r] + bia, 0.0f);
                    h1[(16 + kq * 4 + r) * H1S + n] = fmaxf(acc1[nf][r] + bia, 0.0f);
                }
            }
        }
    }
    asm volatile("s_waitcnt lgkmcnt(0)" ::: "memory");

    // ---- tail: token t = lane&31 (2 dup lane-groups); layers 2/3 + score
    const float* h1r = (const float*)pl + (lane & 31) * H1S;

    float h2[20];
    #pragma unroll
    for (int o = 0; o < 20; ++o) h2[o] = b1b[o];
    #pragma unroll
    for (int i = 0; i < 50; ++i) {
        float hv = h1r[i];
        #pragma unroll
        for (int o = 0; o < 20; ++o) h2[o] = fmaf(hv, W1b[o * 50 + i], h2[o]);
    }
    #pragma unroll
    for (int o = 0; o < 20; ++o) h2[o] = fmaxf(h2[o], 0.0f);

    float h3[20];
    #pragma unroll
    for (int o = 0; o < 20; ++o) {
        float a = b1c[o];
        const float* w = W1c + o * 20;
        #pragma unroll
        for (int i = 0; i < 20; ++i) a = fmaf(h2[i], w[i], a);
        h3[o] = fmaxf(a, 0.0f);
    }

    float s = pb2[0];
    #pragma unroll
    for (int j = 0; j < 10; ++j) {
        float a = pb1[j];
        const float* w = pW1 + j * 20;
        #pragma unroll
        for (int i = 0; i < 20; ++i) a = fmaf(h3[i], w[i], a);
        s = fmaf(fmaxf(a, 0.0f), pW2[j], s);
    }

    // softmax partial over the wave's 32 tokens (d<=16 keeps dup halves apart)
    float m = s;
    #pragma unroll
    for (int d = 16; d > 0; d >>= 1) m = fmaxf(m, __shfl_xor(m, d));
    float e = expf(s - m);
    float S = e;
    #pragma unroll
    for (int d = 16; d > 0; d >>= 1) S += __shfl_xor(S, d);

    float V[20];
    #pragma unroll
    for (int o = 0; o < 20; ++o) {
        float v = e * h3[o];
        #pragma unroll
        for (int d = 16; d > 0; d >>= 1) v += __shfl_xor(v, d);
        V[o] = v;
    }

    // ---- merge the block's two 32-token partials -> one 64-token partial
    float* pm = (float*)(smem + 2 * WPLANE);
    {
        float myv = m;
        if (lane == 1) myv = S;
        #pragma unroll
        for (int o = 0; o < 20; ++o) if (lane == o + 2) myv = V[o];
        if (lane < 22) pm[wv * 24 + lane] = myv;
    }
    __syncthreads();   // only barrier in the kernel (end; nothing in flight)

    if (wv == 0 && lane < 22) {
        float m0 = pm[0], S0 = pm[1], m1 = pm[24], S1 = pm[25];
        float mm = fmaxf(m0, m1);
        float w0 = expf(m0 - mm), w1 = expf(m1 - mm);
        float out;
        if (lane == 0)      out = mm;
        else if (lane == 1) out = fmaf(S0, w0, S1 * w1);
        else                out = fmaf(pm[lane], w0, pm[24 + lane] * w1);
        partials[(size_t)blockIdx.x * 24 + lane] = out;
    }
}

// ---------------------------------------------------------------------------
// Kernel B: combine half-group partials, pool over G=128, normalize, head.
// ---------------------------------------------------------------------------
__global__ __launch_bounds__(128, 4)
void pool_g_head(const float* __restrict__ partials,
                 const float* __restrict__ qW1, const float* __restrict__ qb1,
                 const float* __restrict__ qW2, const float* __restrict__ qb2,
                 const float* __restrict__ W3a, const float* __restrict__ b3a,
                 const float* __restrict__ W3b, const float* __restrict__ b3b,
                 float* __restrict__ out)
{
    __shared__ float red_m[2];
    __shared__ float red_s[2];
    __shared__ float part[2][20];

    const int tid = threadIdx.x;      // g
    const int b = blockIdx.x;
    const float* P = partials + ((size_t)(b * 128 + tid)) * 48;

    float m0 = P[0], S0 = P[1], m1 = P[24], S1 = P[25];
    float m = fmaxf(m0, m1);
    float w0 = expf(m0 - m), w1 = expf(m1 - m);
    float den = fmaf(S0, w0, S1 * w1);

    float v[20];
    #pragma unroll
    for (int o = 0; o < 20; ++o)
        v[o] = fmaf(P[2 + o], w0, P[26 + o] * w1) / den;

    float s = qb2[0];
    #pragma unroll
    for (int j = 0; j < 10; ++j) {
        float a = qb1[j];
        const float* w = qW1 + j * 20;
        #pragma unroll
        for (int i = 0; i < 20; ++i) a = fmaf(v[i], w[i], a);
        s = fmaf(fmaxf(a, 0.0f), qW2[j], s);
    }

    const int wig = tid >> 6, lane = tid & 63;
    float mm = s;
    #pragma unroll
    for (int d = 32; d > 0; d >>= 1) mm = fmaxf(mm, __shfl_xor(mm, d));
    if (lane == 0) red_m[wig] = mm;
    __syncthreads();
    mm = fmaxf(red_m[0], red_m[1]);

    float e = expf(s - mm);
    float su = e;
    #pragma unroll
    for (int d = 32; d > 0; d >>= 1) su += __shfl_xor(su, d);
    if (lane == 0) red_s[wig] = su;

    #pragma unroll
    for (int o = 0; o < 20; ++o) {
        float val = e * v[o];
        #pragma unroll
        for (int d = 32; d > 0; d >>= 1) val += __shfl_xor(val, d);
        if (lane == 0) part[wig][o] = val;
    }
    __syncthreads();

    if (tid == 0) {
        float dg = red_s[0] + red_s[1];
        float rb[20];
        float n2 = 0.0f;
        #pragma unroll
        for (int o = 0; o < 20; ++o) {
            rb[o] = (part[0][o] + part[1][o]) / dg;
            n2 = fmaf(rb[o], rb[o], n2);
        }
        float nrm = fmaxf(sqrtf(n2), 1e-12f);
        #pragma unroll
        for (int o = 0; o < 20; ++o) rb[o] /= nrm;

        float accv = b3b[0];
        #pragma unroll
        for (int j = 0; j < 10; ++j) {
            float a = b3a[j];
            const float* w = W3a + j * 20;
            #pragma unroll
            for (int i = 0; i < 20; ++i) a = fmaf(rb[i], w[i], a);
            accv = fmaf(fmaxf(a, 0.0f), W3b[j], accv);
        }
        out[b] = accv;
    }
}

extern "C" void kernel_launch(void* const* d_in, const int* in_sizes, int n_in,
                              void* d_out, int out_size, void* d_ws, size_t ws_size,
                              hipStream_t stream) {
    const float* x   = (const float*)d_in[0];
    const float* W1a = (const float*)d_in[1];
    const float* b1a = (const float*)d_in[2];
    const float* W1b = (const float*)d_in[3];
    const float* b1b = (const float*)d_in[4];
    const float* W1c = (const float*)d_in[5];
    const float* b1c = (const float*)d_in[6];
    const float* pW1 = (const float*)d_in[7];
    const float* pb1 = (const float*)d_in[8];
    const float* pW2 = (const float*)d_in[9];
    const float* pb2 = (const float*)d_in[10];
    const float* qW1 = (const float*)d_in[11];
    const float* qb1 = (const float*)d_in[12];
    const float* qW2 = (const float*)d_in[13];
    const float* qb2 = (const float*)d_in[14];
    const float* W3a = (const float*)d_in[15];
    const float* b3a = (const float*)d_in[16];
    const float* W3b = (const float*)d_in[17];
    const float* b3b = (const float*)d_in[18];

    float* partials      = (float*)d_ws;                             // 786,432 B
    unsigned short* Bpre = (unsigned short*)((char*)d_ws + 786432);  // 81,920 B

    prep_w<<<160, 256, 0, stream>>>(W1a, Bpre);
    fused_mlp<<<8192, 128, 0, stream>>>(
        x, Bpre, b1a, W1b, b1b, W1c, b1c, pW1, pb1, pW2, pb2, partials);
    pool_g_head<<<32, 128, 0, stream>>>(
        partials, qW1, qb1, qW2, qb2, W3a, b3a, W3b, b3b, (float*)d_out);
}

// Round 12
// 286.885 us; speedup vs baseline: 1.4749x; 1.2025x over previous
//
#include <hip/hip_runtime.h>
#include <hip/hip_bf16.h>
#include <math.h>
#include <stdint.h>

typedef __attribute__((ext_vector_type(8))) short bf16x8;
typedef __attribute__((ext_vector_type(4))) float floatx4;

static __device__ __forceinline__ unsigned short f32_to_bf16_rne(float f) {
    union { float f; uint32_t u; } v; v.f = f;
    uint32_t u = v.u;
    return (unsigned short)((u + 0x7fffu + ((u >> 16) & 1u)) >> 16);
}
static __device__ __forceinline__ float bf16_to_f32(unsigned short h) {
    union { uint32_t u; float f; } v; v.u = ((uint32_t)h) << 16;
    return v.f;
}
// 4 float2 -> bf16x8 via HW v_cvt_pk_bf16_f32 (RNE)
static __device__ __forceinline__ bf16x8 cvt8(const float2* p) {
    union { __hip_bfloat162 h[4]; bf16x8 v; } u;
    #pragma unroll
    for (int j = 0; j < 4; ++j)
        u.h[j] = __float22bfloat162_rn({p[j].x, p[j].y});
    return u.v;
}

// ---------------------------------------------------------------------------
// Prep: W1a (50x318) -> hi/lo bf16, fragment-ordered:
// byte = ks*8192 + p*4096 + kq*1024 + n*16  (n in [0,64), zero-padded)
// ---------------------------------------------------------------------------
__global__ void prep_w(const float* __restrict__ W1a, unsigned short* __restrict__ Bpre) {
    int idx = blockIdx.x * 256 + threadIdx.x;
    if (idx >= 40960) return;
    int e  = idx & 7;
    int n  = (idx >> 3) & 63;
    int kq = (idx >> 9) & 3;
    int p  = (idx >> 11) & 1;
    int ks = idx >> 12;
    int k  = ks * 32 + kq * 8 + e;
    float w = (n < 50 && k < 318) ? W1a[n * 318 + k] : 0.0f;
    unsigned short hi = f32_to_bf16_rne(w);
    Bpre[idx] = (p == 0) ? hi : f32_to_bf16_rne(w - bf16_to_f32(hi));
}

// ---------------------------------------------------------------------------
// Kernel A: 8192 blocks (64-token slab), 256 threads (4 waves), 3 blocks/CU.
// M-SLICED waves: wave wv owns tokens [wv*16, wv*16+16) x ALL n. A-fragments
// loaded DIRECTLY global->reg (two pinned 20-load bursts, 40 VGPR), converted
// via v_cvt_pk_bf16_f32, MFMA'd against per-ks transient B (hi/lo, L2-hot).
// No LDS staging, no pack VALU, no GEMM barriers. h1 exchange via wave-private
// LDS patch (intra-wave, lgkm only). Tail: token = fr, 4x lane-redundant.
// One __syncthreads to merge 4 wave-partials -> 64-token partial.
// ---------------------------------------------------------------------------
#define SLAB (64 * 318)
#define H1S 52                     // h1 row stride (floats), even for b64 reads
#define WPATCH (16 * H1S)          // floats per wave patch

__global__ __launch_bounds__(256, 3)
void fused_mlp(const float* __restrict__ x,
               const unsigned short* __restrict__ Bpre,
               const float* __restrict__ b1a,
               const float* __restrict__ W1b, const float* __restrict__ b1b,
               const float* __restrict__ W1c, const float* __restrict__ b1c,
               const float* __restrict__ pW1, const float* __restrict__ pb1,
               const float* __restrict__ pW2, const float* __restrict__ pb2,
               float* __restrict__ partials)
{
    __shared__ __align__(16) float hbuf[4 * WPATCH];   // 13312 B
    __shared__ float pm[4][24];

    const int tid  = threadIdx.x;
    const int wv   = tid >> 6;
    const int lane = tid & 63;
    const int fr   = lane & 15;
    const int kq   = lane >> 4;

    // lane's A row pointer: token row wv*16+fr, k-base kq*8
    const float* arow = x + (size_t)blockIdx.x * SLAB + (wv * 16 + fr) * 318 + kq * 8;

    float2 af[20];
    floatx4 acc[4];
    #pragma unroll
    for (int nf = 0; nf < 4; ++nf) acc[nf] = (floatx4){0.f, 0.f, 0.f, 0.f};

    // ---- burst 0: ks 0..4 A-fragments (20 x float2, 8B-aligned, 32B/lane/ks)
    #pragma unroll
    for (int ks = 0; ks < 5; ++ks)
        #pragma unroll
        for (int j = 0; j < 4; ++j)
            af[ks * 4 + j] = *(const float2*)(arow + ks * 32 + 2 * j);
    __builtin_amdgcn_sched_barrier(0);   // pin burst issue before compute

    #pragma unroll
    for (int ks = 0; ks < 5; ++ks) {
        const char* bb = (const char*)Bpre + ks * 8192 + (kq << 10) + (fr << 4);
        bf16x8 a = cvt8(&af[ks * 4]);
        #pragma unroll
        for (int nf = 0; nf < 4; ++nf) {
            bf16x8 bh = *(const bf16x8*)(bb + nf * 256);
            bf16x8 bl = *(const bf16x8*)(bb + 4096 + nf * 256);
            acc[nf] = __builtin_amdgcn_mfma_f32_16x16x32_bf16(a, bh, acc[nf], 0, 0, 0);
            acc[nf] = __builtin_amdgcn_mfma_f32_16x16x32_bf16(a, bl, acc[nf], 0, 0, 0);
        }
    }

    // ---- burst 1: ks 5..9 (ks=9,kq=3,j=3 would be k=318,319 -> zero pad)
    #pragma unroll
    for (int ks = 5; ks < 10; ++ks)
        #pragma unroll
        for (int j = 0; j < 4; ++j) {
            bool pad = (ks == 9) && (kq == 3) && (j == 3);
            af[(ks - 5) * 4 + j] = pad ? make_float2(0.f, 0.f)
                                       : *(const float2*)(arow + ks * 32 + 2 * j);
        }
    __builtin_amdgcn_sched_barrier(0);

    #pragma unroll
    for (int ks = 5; ks < 10; ++ks) {
        const char* bb = (const char*)Bpre + ks * 8192 + (kq << 10) + (fr << 4);
        bf16x8 a = cvt8(&af[(ks - 5) * 4]);
        #pragma unroll
        for (int nf = 0; nf < 4; ++nf) {
            bf16x8 bh = *(const bf16x8*)(bb + nf * 256);
            bf16x8 bl = *(const bf16x8*)(bb + 4096 + nf * 256);
            acc[nf] = __builtin_amdgcn_mfma_f32_16x16x32_bf16(a, bh, acc[nf], 0, 0, 0);
            acc[nf] = __builtin_amdgcn_mfma_f32_16x16x32_bf16(a, bl, acc[nf], 0, 0, 0);
        }
    }

    // ---- bias + ReLU -> wave-private h1 patch [16 tokens][52]
    // D layout: lane (fr,kq), acc[nf][r] = h1[token kq*4+r][n = nf*16+fr]
    float* h1p = hbuf + wv * WPATCH;
    #pragma unroll
    for (int nf = 0; nf < 4; ++nf) {
        int n = nf * 16 + fr;
        if (n < 50) {
            float bia = b1a[n];
            #pragma unroll
            for (int r = 0; r < 4; ++r)
                h1p[(kq * 4 + r) * H1S + n] = fmaxf(acc[nf][r] + bia, 0.0f);
        }
    }
    asm volatile("s_waitcnt lgkmcnt(0)" ::: "memory");   // intra-wave ordering

    // ---- tail: token = fr (each token processed by 4 lanes redundantly)
    const float* h1r = h1p + fr * H1S;

    float h2[20];
    #pragma unroll
    for (int o = 0; o < 20; ++o) h2[o] = b1b[o];
    #pragma unroll
    for (int i = 0; i < 50; ++i) {
        float hv = h1r[i];
        #pragma unroll
        for (int o = 0; o < 20; ++o) h2[o] = fmaf(hv, W1b[o * 50 + i], h2[o]);
    }
    #pragma unroll
    for (int o = 0; o < 20; ++o) h2[o] = fmaxf(h2[o], 0.0f);

    float h3[20];
    #pragma unroll
    for (int o = 0; o < 20; ++o) {
        float a = b1c[o];
        const float* w = W1c + o * 20;
        #pragma unroll
        for (int i = 0; i < 20; ++i) a = fmaf(h2[i], w[i], a);
        h3[o] = fmaxf(a, 0.0f);
    }

    float s = pb2[0];
    #pragma unroll
    for (int j = 0; j < 10; ++j) {
        float a = pb1[j];
        const float* w = pW1 + j * 20;
        #pragma unroll
        for (int i = 0; i < 20; ++i) a = fmaf(h3[i], w[i], a);
        s = fmaf(fmaxf(a, 0.0f), pW2[j], s);
    }

    // softmax partial over the wave's 16 tokens (reduce over fr bits 1,2,4,8)
    float m = s;
    #pragma unroll
    for (int d = 8; d > 0; d >>= 1) m = fmaxf(m, __shfl_xor(m, d));
    float e = expf(s - m);
    float S = e;
    #pragma unroll
    for (int d = 8; d > 0; d >>= 1) S += __shfl_xor(S, d);

    float V[20];
    #pragma unroll
    for (int o = 0; o < 20; ++o) {
        float v = e * h3[o];
        #pragma unroll
        for (int d = 8; d > 0; d >>= 1) v += __shfl_xor(v, d);
        V[o] = v;
    }

    // wave partial {m, S, V[20]} -> pm[wv]
    {
        float myv = m;
        if (lane == 1) myv = S;
        #pragma unroll
        for (int o = 0; o < 20; ++o) if (lane == o + 2) myv = V[o];
        if (lane < 22) pm[wv][lane] = myv;
    }
    __syncthreads();   // only block barrier (nothing left in flight)

    // wave 0 merges the 4 wave-partials -> 64-token partial (same format)
    if (wv == 0 && lane < 22) {
        float m0 = pm[0][0], m1 = pm[1][0], m2 = pm[2][0], m3 = pm[3][0];
        float mm = fmaxf(fmaxf(m0, m1), fmaxf(m2, m3));
        float w0 = expf(m0 - mm), w1 = expf(m1 - mm);
        float w2 = expf(m2 - mm), w3 = expf(m3 - mm);
        float out;
        if (lane == 0) {
            out = mm;
        } else {
            float v0 = pm[0][lane], v1 = pm[1][lane];
            float v2 = pm[2][lane], v3 = pm[3][lane];
            out = fmaf(v0, w0, fmaf(v1, w1, fmaf(v2, w2, v3 * w3)));
        }
        partials[(size_t)blockIdx.x * 24 + lane] = out;
    }
}

// ---------------------------------------------------------------------------
// Kernel B: combine half-group partials, pool over G=128, normalize, head.
// ---------------------------------------------------------------------------
__global__ __launch_bounds__(128, 4)
void pool_g_head(const float* __restrict__ partials,
                 const float* __restrict__ qW1, const float* __restrict__ qb1,
                 const float* __restrict__ qW2, const float* __restrict__ qb2,
                 const float* __restrict__ W3a, const float* __restrict__ b3a,
                 const float* __restrict__ W3b, const float* __restrict__ b3b,
                 float* __restrict__ out)
{
    __shared__ float red_m[2];
    __shared__ float red_s[2];
    __shared__ float part[2][20];

    const int tid = threadIdx.x;      // g
    const int b = blockIdx.x;
    const float* P = partials + ((size_t)(b * 128 + tid)) * 48;

    float m0 = P[0], S0 = P[1], m1 = P[24], S1 = P[25];
    float m = fmaxf(m0, m1);
    float w0 = expf(m0 - m), w1 = expf(m1 - m);
    float den = fmaf(S0, w0, S1 * w1);

    float v[20];
    #pragma unroll
    for (int o = 0; o < 20; ++o)
        v[o] = fmaf(P[2 + o], w0, P[26 + o] * w1) / den;

    float s = qb2[0];
    #pragma unroll
    for (int j = 0; j < 10; ++j) {
        float a = qb1[j];
        const float* w = qW1 + j * 20;
        #pragma unroll
        for (int i = 0; i < 20; ++i) a = fmaf(v[i], w[i], a);
        s = fmaf(fmaxf(a, 0.0f), qW2[j], s);
    }

    const int wig = tid >> 6, lane = tid & 63;
    float mm = s;
    #pragma unroll
    for (int d = 32; d > 0; d >>= 1) mm = fmaxf(mm, __shfl_xor(mm, d));
    if (lane == 0) red_m[wig] = mm;
    __syncthreads();
    mm = fmaxf(red_m[0], red_m[1]);

    float e = expf(s - mm);
    float su = e;
    #pragma unroll
    for (int d = 32; d > 0; d >>= 1) su += __shfl_xor(su, d);
    if (lane == 0) red_s[wig] = su;

    #pragma unroll
    for (int o = 0; o < 20; ++o) {
        float val = e * v[o];
        #pragma unroll
        for (int d = 32; d > 0; d >>= 1) val += __shfl_xor(val, d);
        if (lane == 0) part[wig][o] = val;
    }
    __syncthreads();

    if (tid == 0) {
        float dg = red_s[0] + red_s[1];
        float rb[20];
        float n2 = 0.0f;
        #pragma unroll
        for (int o = 0; o < 20; ++o) {
            rb[o] = (part[0][o] + part[1][o]) / dg;
            n2 = fmaf(rb[o], rb[o], n2);
        }
        float nrm = fmaxf(sqrtf(n2), 1e-12f);
        #pragma unroll
        for (int o = 0; o < 20; ++o) rb[o] /= nrm;

        float accv = b3b[0];
        #pragma unroll
        for (int j = 0; j < 10; ++j) {
            float a = b3a[j];
            const float* w = W3a + j * 20;
            #pragma unroll
            for (int i = 0; i < 20; ++i) a = fmaf(rb[i], w[i], a);
            accv = fmaf(fmaxf(a, 0.0f), W3b[j], accv);
        }
        out[b] = accv;
    }
}

extern "C" void kernel_launch(void* const* d_in, const int* in_sizes, int n_in,
                              void* d_out, int out_size, void* d_ws, size_t ws_size,
                              hipStream_t stream) {
    const float* x   = (const float*)d_in[0];
    const float* W1a = (const float*)d_in[1];
    const float* b1a = (const float*)d_in[2];
    const float* W1b = (const float*)d_in[3];
    const float* b1b = (const float*)d_in[4];
    const float* W1c = (const float*)d_in[5];
    const float* b1c = (const float*)d_in[6];
    const float* pW1 = (const float*)d_in[7];
    const float* pb1 = (const float*)d_in[8];
    const float* pW2 = (const float*)d_in[9];
    const float* pb2 = (const float*)d_in[10];
    const float* qW1 = (const float*)d_in[11];
    const float* qb1 = (const float*)d_in[12];
    const float* qW2 = (const float*)d_in[13];
    const float* qb2 = (const float*)d_in[14];
    const float* W3a = (const float*)d_in[15];
    const float* b3a = (const float*)d_in[16];
    const float* W3b = (const float*)d_in[17];
    const float* b3b = (const float*)d_in[18];

    float* partials      = (float*)d_ws;                             // 786,432 B
    unsigned short* Bpre = (unsigned short*)((char*)d_ws + 786432);  // 81,920 B

    prep_w<<<160, 256, 0, stream>>>(W1a, Bpre);
    fused_mlp<<<8192, 256, 0, stream>>>(
        x, Bpre, b1a, W1b, b1b, W1c, b1c, pW1, pb1, pW2, pb2, partials);
    pool_g_head<<<32, 128, 0, stream>>>(
        partials, qW1, qb1, qW2, qb2, W3a, b3a, W3b, b3b, (float*)d_out);
}